// Round 1
// baseline (542.935 us; speedup 1.0000x reference)
//
#include <hip/hip_runtime.h>
#include <math.h>

// LambdaLayer: B=32, DIM=512, H=W=32 (N=1024), DIM_K=16, HEADS=4, DIM_V=128, R=15
#define BATCH 32
#define DIMC  512
#define HGT   32
#define WID   32
#define NPOS  1024
#define DK    16
#define NHEADS 4
#define DV    128
#define RR    15
#define NQ    64   // DK*NHEADS

// workspace layout in floats
static constexpr size_t WS_Q  = 0;                                  // [B][64][1024]
static constexpr size_t WS_K  = WS_Q + (size_t)BATCH * NQ * NPOS;   // [B][16][1024] (softmaxed)
static constexpr size_t WS_V  = WS_K + (size_t)BATCH * DK * NPOS;   // [B][128][1024]
static constexpr size_t WS_CL = WS_V + (size_t)BATCH * DV * NPOS;   // [B][16][128]

// ---------------------------------------------------------------------------
// K1: projections (q,k,v) as GEMM chunks of 16 output channels, fused BN for
// q/v and channel-softmax for k. grid = B * 4(n-tiles of 256) * 13(o-chunks).
// o-chunks: 0..3 -> q rows 0..63 ; 4 -> k rows 0..15 ; 5..12 -> v rows 0..127
// ---------------------------------------------------------------------------
__global__ __launch_bounds__(256) void proj_kernel(
    const float* __restrict__ x,  const float* __restrict__ wq,
    const float* __restrict__ wk, const float* __restrict__ wv,
    const float* __restrict__ qg, const float* __restrict__ qb,
    const float* __restrict__ vg, const float* __restrict__ vb,
    float* __restrict__ ws)
{
    __shared__ float w_l[16 * 512];   // 32 KB weight chunk

    const int t  = threadIdx.x;
    const int c  = blockIdx.x % 13;
    const int nt = (blockIdx.x / 13) & 3;
    const int b  = blockIdx.x / 52;

    const float* wsrc;
    if (c < 4)       wsrc = wq + (size_t)c * 16 * 512;
    else if (c == 4) wsrc = wk;
    else             wsrc = wv + (size_t)(c - 5) * 16 * 512;

    // stage 16x512 weights (contiguous rows) as float4
    {
        const float4* s4 = (const float4*)wsrc;
        float4* d4 = (float4*)w_l;
        #pragma unroll
        for (int i = 0; i < 8; i++) d4[t + i * 256] = s4[t + i * 256];
    }
    __syncthreads();

    const int n = nt * 256 + t;
    float acc[16];
    #pragma unroll
    for (int o = 0; o < 16; o++) acc[o] = 0.f;

    const float* xb = x + (size_t)b * DIMC * NPOS + n;
    for (int d0 = 0; d0 < 512; d0 += 4) {
        float xv0 = xb[(size_t)(d0 + 0) * NPOS];
        float xv1 = xb[(size_t)(d0 + 1) * NPOS];
        float xv2 = xb[(size_t)(d0 + 2) * NPOS];
        float xv3 = xb[(size_t)(d0 + 3) * NPOS];
        #pragma unroll
        for (int o = 0; o < 16; o++) {
            float4 w4 = *(const float4*)&w_l[o * 512 + d0];
            acc[o] = fmaf(w4.x, xv0, acc[o]);
            acc[o] = fmaf(w4.y, xv1, acc[o]);
            acc[o] = fmaf(w4.z, xv2, acc[o]);
            acc[o] = fmaf(w4.w, xv3, acc[o]);
        }
    }

    const float bninv = 1.0f / sqrtf(1.0f + 1e-5f);

    if (c < 4) {                      // q rows + BN
        #pragma unroll
        for (int o = 0; o < 16; o++) {
            int oc = c * 16 + o;
            float val = acc[o] * (qg[oc] * bninv) + qb[oc];
            ws[WS_Q + ((size_t)b * NQ + oc) * NPOS + n] = val;
        }
    } else if (c == 4) {              // k rows -> softmax over the 16 channels
        float m = acc[0];
        #pragma unroll
        for (int o = 1; o < 16; o++) m = fmaxf(m, acc[o]);
        float s = 0.f;
        #pragma unroll
        for (int o = 0; o < 16; o++) { acc[o] = __expf(acc[o] - m); s += acc[o]; }
        float r = 1.0f / s;
        #pragma unroll
        for (int o = 0; o < 16; o++)
            ws[WS_K + ((size_t)b * DK + o) * NPOS + n] = acc[o] * r;
    } else {                          // v rows + BN
        #pragma unroll
        for (int o = 0; o < 16; o++) {
            int vc = (c - 5) * 16 + o;
            float val = acc[o] * (vg[vc] * bninv) + vb[vc];
            ws[WS_V + ((size_t)b * DV + vc) * NPOS + n] = val;
        }
    }
}

// ---------------------------------------------------------------------------
// K2: content_lambda[b,k,v] = sum_n ksm[b,k,n] * v[b,v,n]
// grid = B*DV blocks of 1 wave (64 threads); coalesced over n; shuffle-reduce.
// ---------------------------------------------------------------------------
__global__ __launch_bounds__(64) void cl_kernel(float* __restrict__ ws)
{
    const int lane = threadIdx.x;
    const int v = blockIdx.x % DV;
    const int b = blockIdx.x / DV;

    const float* vrow  = ws + WS_V + ((size_t)b * DV + v) * NPOS;
    const float* krows = ws + WS_K + (size_t)b * DK * NPOS;

    float acc[16];
    #pragma unroll
    for (int k = 0; k < 16; k++) acc[k] = 0.f;

    for (int i = 0; i < 16; i++) {
        int n = i * 64 + lane;
        float vv = vrow[n];
        #pragma unroll
        for (int k = 0; k < 16; k++)
            acc[k] = fmaf(krows[(size_t)k * NPOS + n], vv, acc[k]);
    }

    #pragma unroll
    for (int k = 0; k < 16; k++) {
        float s = acc[k];
        #pragma unroll
        for (int off = 32; off > 0; off >>= 1) s += __shfl_down(s, off);
        if (lane == 0) ws[WS_CL + ((size_t)b * DK + k) * DV + v] = s;
    }
}

// ---------------------------------------------------------------------------
// K3: out[b, h*128+v, y, x] = sum_k q[b,h,k,n] * cl[b,k,v]
//                           + sum_{dy,dx} qe[b,h,n,dy,dx] * v[b,v,y+dy-7,x+dx-7]
// where qe[h,n,dy,dx] = sum_k q[b,h,k,n]*emb[k,dy,dx].
// One block per (b, y-row). 256 threads = (vgroup 0..7) x (x 0..31); each
// thread accumulates 4 heads x 16 v-channels for its x.
// ---------------------------------------------------------------------------
__global__ __launch_bounds__(256) void out_kernel(
    const float* __restrict__ emb, const float* __restrict__ ws,
    float* __restrict__ out)
{
    __shared__ float q_l[NQ * 32];            // [o][x]        8 KB
    __shared__ float cl_l[DK * DV];           // [k][v]        8 KB
    __shared__ float emb_l[DK * RR * RR];     // [k][dy][dx]  14.4 KB
    __shared__ float qe_l[NHEADS * RR * 32];  // [h][dx][x]    7.7 KB
    __shared__ float v_l[DV][48];             // padded slab  24 KB

    const int t = threadIdx.x;
    const int b = blockIdx.x >> 5;
    const int y = blockIdx.x & 31;
    const int x = t & 31;
    const int vbase = (t >> 5) * 16;

    // stage q row-slab (64 ch x 32 x), cl (16x128), emb (3600)
    {
        const float* qsrc = ws + WS_Q + (size_t)b * NQ * NPOS + y * 32;
        #pragma unroll
        for (int i = 0; i < 8; i++) {
            int idx = t + i * 256;            // 0..2047
            int o = idx >> 5, xx = idx & 31;
            q_l[idx] = qsrc[(size_t)o * NPOS + xx];
        }
        const float* clsrc = ws + WS_CL + (size_t)b * DK * DV;
        #pragma unroll
        for (int i = 0; i < 8; i++) { int idx = t + i * 256; cl_l[idx] = clsrc[idx]; }
        for (int idx = t; idx < DK * RR * RR; idx += 256) emb_l[idx] = emb[idx];
    }
    __syncthreads();

    float acc[4][16];
    #pragma unroll
    for (int h = 0; h < 4; h++)
        #pragma unroll
        for (int iv = 0; iv < 16; iv++) acc[h][iv] = 0.f;

    // content term: acc[h][iv] += q[h,k,x] * cl[k, vbase+iv]
    #pragma unroll
    for (int k = 0; k < DK; k++) {
        float qv0 = q_l[(0 * 16 + k) * 32 + x];
        float qv1 = q_l[(1 * 16 + k) * 32 + x];
        float qv2 = q_l[(2 * 16 + k) * 32 + x];
        float qv3 = q_l[(3 * 16 + k) * 32 + x];
        #pragma unroll
        for (int iv = 0; iv < 16; iv++) {
            float cv = cl_l[k * DV + vbase + iv];
            acc[0][iv] = fmaf(qv0, cv, acc[0][iv]);
            acc[1][iv] = fmaf(qv1, cv, acc[1][iv]);
            acc[2][iv] = fmaf(qv2, cv, acc[2][iv]);
            acc[3][iv] = fmaf(qv3, cv, acc[3][iv]);
        }
    }

    // position term
    const float* vsrcb = ws + WS_V + (size_t)b * DV * NPOS;
    for (int dy = 0; dy < RR; dy++) {
        int yy = y + dy - 7;
        bool yok = (yy >= 0) && (yy < HGT);
        __syncthreads();   // previous iteration's readers done

        // stage padded v slab: v_l[vch][7 + xx] = v[b, vch, yy, xx], zeros outside
        for (int i = t; i < DV * 48; i += 256) {
            int vch = i / 48, cc = i - vch * 48;
            int xx = cc - 7;
            float val = 0.f;
            if (yok && xx >= 0 && xx < WID)
                val = vsrcb[(size_t)vch * NPOS + yy * 32 + xx];
            v_l[vch][cc] = val;
        }
        // qe[h][dx][x] = sum_k q[h,k,x] * emb[k,dy,dx]  (1920 values)
        for (int i = t; i < NHEADS * RR * 32; i += 256) {
            int h = i / (RR * 32);
            int rem = i - h * (RR * 32);
            int dx = rem >> 5, xx = rem & 31;
            float s = 0.f;
            #pragma unroll
            for (int k = 0; k < DK; k++)
                s = fmaf(q_l[(h * 16 + k) * 32 + xx], emb_l[(k * RR + dy) * RR + dx], s);
            qe_l[i] = s;
        }
        __syncthreads();

        #pragma unroll 1
        for (int dx = 0; dx < RR; dx++) {
            float qv0 = qe_l[(0 * RR + dx) * 32 + x];
            float qv1 = qe_l[(1 * RR + dx) * 32 + x];
            float qv2 = qe_l[(2 * RR + dx) * 32 + x];
            float qv3 = qe_l[(3 * RR + dx) * 32 + x];
            int col = x + dx;   // x + dx - 7 + 7
            #pragma unroll
            for (int iv = 0; iv < 16; iv++) {
                float vv = v_l[vbase + iv][col];
                acc[0][iv] = fmaf(qv0, vv, acc[0][iv]);
                acc[1][iv] = fmaf(qv1, vv, acc[1][iv]);
                acc[2][iv] = fmaf(qv2, vv, acc[2][iv]);
                acc[3][iv] = fmaf(qv3, vv, acc[3][iv]);
            }
        }
    }

    // store: out[b, h*128 + vbase+iv, y*32 + x]
    float* ob = out + (size_t)b * 512 * NPOS + y * 32 + x;
    #pragma unroll
    for (int h = 0; h < 4; h++)
        #pragma unroll
        for (int iv = 0; iv < 16; iv++)
            ob[(size_t)(h * 128 + vbase + iv) * NPOS] = acc[h][iv];
}

// ---------------------------------------------------------------------------
extern "C" void kernel_launch(void* const* d_in, const int* in_sizes, int n_in,
                              void* d_out, int out_size, void* d_ws, size_t ws_size,
                              hipStream_t stream)
{
    const float* x   = (const float*)d_in[0];
    const float* wq  = (const float*)d_in[1];
    const float* wk  = (const float*)d_in[2];
    const float* wv  = (const float*)d_in[3];
    const float* emb = (const float*)d_in[4];
    const float* qg  = (const float*)d_in[5];
    const float* qb  = (const float*)d_in[6];
    const float* vg  = (const float*)d_in[7];
    const float* vb  = (const float*)d_in[8];
    float* out = (float*)d_out;
    float* ws  = (float*)d_ws;

    hipLaunchKernelGGL(proj_kernel, dim3(BATCH * 4 * 13), dim3(256), 0, stream,
                       x, wq, wk, wv, qg, qb, vg, vb, ws);
    hipLaunchKernelGGL(cl_kernel, dim3(BATCH * DV), dim3(64), 0, stream, ws);
    hipLaunchKernelGGL(out_kernel, dim3(BATCH * 32), dim3(256), 0, stream, emb, ws, out);
}

// Round 2
// 350.889 us; speedup vs baseline: 1.5473x; 1.5473x over previous
//
#include <hip/hip_runtime.h>
#include <hip/hip_bf16.h>
#include <math.h>

// LambdaLayer: B=32, DIM=512, H=W=32 (N=1024), DIM_K=16, HEADS=4, DIM_V=128, R=15
#define BATCH 32
#define DIMC  512
#define HGT   32
#define WID   32
#define NPOS  1024
#define DK    16
#define NHEADS 4
#define DV    128
#define RR    15
#define NQ    64   // DK*NHEADS

typedef __attribute__((ext_vector_type(8))) short short8;
typedef __attribute__((ext_vector_type(4))) float f32x4;

// workspace layout in floats
static constexpr size_t WS_Q  = 0;                                  // [B][64][1024]
static constexpr size_t WS_K  = WS_Q + (size_t)BATCH * NQ * NPOS;   // [B][16][1024] (softmaxed)
static constexpr size_t WS_V  = WS_K + (size_t)BATCH * DK * NPOS;   // [B][128][1024]
static constexpr size_t WS_CL = WS_V + (size_t)BATCH * DV * NPOS;   // [B][16][128]

static __device__ __forceinline__ unsigned f2bf(float f) {
    return (unsigned)__builtin_bit_cast(unsigned short, __float2bfloat16(f));
}

// ---------------------------------------------------------------------------
// K1: projections (unchanged from R1 — fp32, works)
// ---------------------------------------------------------------------------
__global__ __launch_bounds__(256) void proj_kernel(
    const float* __restrict__ x,  const float* __restrict__ wq,
    const float* __restrict__ wk, const float* __restrict__ wv,
    const float* __restrict__ qg, const float* __restrict__ qb,
    const float* __restrict__ vg, const float* __restrict__ vb,
    float* __restrict__ ws)
{
    __shared__ float w_l[16 * 512];

    const int t  = threadIdx.x;
    const int c  = blockIdx.x % 13;
    const int nt = (blockIdx.x / 13) & 3;
    const int b  = blockIdx.x / 52;

    const float* wsrc;
    if (c < 4)       wsrc = wq + (size_t)c * 16 * 512;
    else if (c == 4) wsrc = wk;
    else             wsrc = wv + (size_t)(c - 5) * 16 * 512;

    {
        const float4* s4 = (const float4*)wsrc;
        float4* d4 = (float4*)w_l;
        #pragma unroll
        for (int i = 0; i < 8; i++) d4[t + i * 256] = s4[t + i * 256];
    }
    __syncthreads();

    const int n = nt * 256 + t;
    float acc[16];
    #pragma unroll
    for (int o = 0; o < 16; o++) acc[o] = 0.f;

    const float* xb = x + (size_t)b * DIMC * NPOS + n;
    for (int d0 = 0; d0 < 512; d0 += 4) {
        float xv0 = xb[(size_t)(d0 + 0) * NPOS];
        float xv1 = xb[(size_t)(d0 + 1) * NPOS];
        float xv2 = xb[(size_t)(d0 + 2) * NPOS];
        float xv3 = xb[(size_t)(d0 + 3) * NPOS];
        #pragma unroll
        for (int o = 0; o < 16; o++) {
            float4 w4 = *(const float4*)&w_l[o * 512 + d0];
            acc[o] = fmaf(w4.x, xv0, acc[o]);
            acc[o] = fmaf(w4.y, xv1, acc[o]);
            acc[o] = fmaf(w4.z, xv2, acc[o]);
            acc[o] = fmaf(w4.w, xv3, acc[o]);
        }
    }

    const float bninv = 1.0f / sqrtf(1.0f + 1e-5f);

    if (c < 4) {
        #pragma unroll
        for (int o = 0; o < 16; o++) {
            int oc = c * 16 + o;
            float val = acc[o] * (qg[oc] * bninv) + qb[oc];
            ws[WS_Q + ((size_t)b * NQ + oc) * NPOS + n] = val;
        }
    } else if (c == 4) {
        float m = acc[0];
        #pragma unroll
        for (int o = 1; o < 16; o++) m = fmaxf(m, acc[o]);
        float s = 0.f;
        #pragma unroll
        for (int o = 0; o < 16; o++) { acc[o] = __expf(acc[o] - m); s += acc[o]; }
        float r = 1.0f / s;
        #pragma unroll
        for (int o = 0; o < 16; o++)
            ws[WS_K + ((size_t)b * DK + o) * NPOS + n] = acc[o] * r;
    } else {
        #pragma unroll
        for (int o = 0; o < 16; o++) {
            int vc = (c - 5) * 16 + o;
            float val = acc[o] * (vg[vc] * bninv) + vb[vc];
            ws[WS_V + ((size_t)b * DV + vc) * NPOS + n] = val;
        }
    }
}

// ---------------------------------------------------------------------------
// K2: content_lambda (unchanged from R1)
// ---------------------------------------------------------------------------
__global__ __launch_bounds__(64) void cl_kernel(float* __restrict__ ws)
{
    const int lane = threadIdx.x;
    const int v = blockIdx.x % DV;
    const int b = blockIdx.x / DV;

    const float* vrow  = ws + WS_V + ((size_t)b * DV + v) * NPOS;
    const float* krows = ws + WS_K + (size_t)b * DK * NPOS;

    float acc[16];
    #pragma unroll
    for (int k = 0; k < 16; k++) acc[k] = 0.f;

    for (int i = 0; i < 16; i++) {
        int n = i * 64 + lane;
        float vv = vrow[n];
        #pragma unroll
        for (int k = 0; k < 16; k++)
            acc[k] = fmaf(krows[(size_t)k * NPOS + n], vv, acc[k]);
    }

    #pragma unroll
    for (int k = 0; k < 16; k++) {
        float s = acc[k];
        #pragma unroll
        for (int off = 32; off > 0; off >>= 1) s += __shfl_down(s, off);
        if (lane == 0) ws[WS_CL + ((size_t)b * DK + k) * DV + v] = s;
    }
}

// ---------------------------------------------------------------------------
// K3 (MFMA): per block (b,y): Out[v=128][(h,x)=128] as banded GEMM.
//   K-structure: 8 "pairs": pairs 0..6 = dy {2p,2p+1}, K=96 (3 chunks of 32);
//   pair 7 = dy 14 (48 cols) + content chunk (cl/q, 16 cols), K=64 (2 chunks).
//   A[v][k]  = bf16 v-slab: image at cols dyl*48+8..+39 (image col = cA-8).
//   Bt[c][k] = bf16 qe band: Bt[h*32+x][dyl*48 + x+dx+1] = qe[h,dy,dx].
//   => Out += qe[h,dy,dx] * v[v, y+dy-7, x+dx-7]  (A zero-padding = SAME conv).
//   Rows padded to 104 halfwords (208 B) => frag b128 reads are ~2-way (free).
// ---------------------------------------------------------------------------
#define ROWHW 104

__global__ __launch_bounds__(256) void out_kernel(
    const float* __restrict__ emb, const float* __restrict__ ws,
    float* __restrict__ out)
{
    __shared__ short A_l[DV * ROWHW];       // 26624 B
    __shared__ short B_l[128 * ROWHW];      // 26624 B
    __shared__ short embp[DK * RR * 16];    // bf16 [k][dy][dx pad16], 7680 B

    const int t = threadIdx.x;
    const int b = blockIdx.x >> 5;
    const int y = blockIdx.x & 31;
    const int lane = t & 63;
    const int w = t >> 6;
    const int wm = (w & 1) * 64;    // v-tile base
    const int wn = (w >> 1) * 64;   // c-tile base
    const int r15 = lane & 15;
    const int sl  = lane >> 4;

    // B-build thread identity: 2 threads per output column c
    const int c    = t >> 1;        // 0..127
    const int h    = c >> 5;
    const int x    = c & 31;
    const int half = t & 1;

    // ---- one-time init: zero A/B (stale-cell safety), stage emb (bf16, padded)
    {
        int* a4 = (int*)A_l; int* b4 = (int*)B_l;   // 6656 dwords each
        for (int i = t; i < 6656; i += 256) { a4[i] = 0; b4[i] = 0; }
    }
    for (int i = t; i < DK * RR * 16; i += 256) {
        int kd = i >> 4, dx = i & 15;
        float val = (dx < RR) ? emb[kd * RR + dx] : 0.f;
        B_l[0] = B_l[0];  // no-op
        ((unsigned short*)embp)[i] = (unsigned short)f2bf(val);
    }
    // hoist this thread's 16 q values (h,x fixed) into VGPRs
    float qv[16];
    {
        const float* qp = ws + WS_Q + ((size_t)b * NQ + h * 16) * NPOS + y * 32 + x;
        #pragma unroll
        for (int k = 0; k < 16; k++) qv[k] = qp[(size_t)k * NPOS];
    }
    __syncthreads();

    auto build = [&](int p) {
        // ---- A operand: 2048 (v,dyl,j) jobs over 8 reps
        #pragma unroll
        for (int rep = 0; rep < 8; rep++) {
            int idx = rep * 256 + t;
            int v   = idx >> 4;
            int dyl = (idx >> 3) & 1;
            int j   = idx & 7;
            if (p == 7 && dyl == 1) {
                // content chunk: A[v][48+2j .. 48+2j+1] = cl[2j][v], cl[2j+1][v]
                float c0 = ws[WS_CL + ((size_t)b * DK + 2 * j    ) * DV + v];
                float c1 = ws[WS_CL + ((size_t)b * DK + 2 * j + 1) * DV + v];
                *(int*)&A_l[v * ROWHW + 48 + 2 * j] = f2bf(c0) | (f2bf(c1) << 16);
            } else {
                int dy = 2 * p + dyl;
                int yy = y + dy - 7;
                float4 val = make_float4(0.f, 0.f, 0.f, 0.f);
                if (yy >= 0 && yy < HGT)
                    val = *(const float4*)&ws[WS_V + ((size_t)b * DV + v) * NPOS + yy * 32 + 4 * j];
                int2 sv;
                sv.x = f2bf(val.x) | (f2bf(val.y) << 16);
                sv.y = f2bf(val.z) | (f2bf(val.w) << 16);
                *(int2*)&A_l[v * ROWHW + dyl * 48 + 8 + 4 * j] = sv;
            }
        }
        // ---- B operand: qe band (or content q on pair 7 / dyl 1)
        #pragma unroll
        for (int dyl = 0; dyl < 2; dyl++) {
            if (p == 7 && dyl == 1) {
                #pragma unroll
                for (int j2 = 0; j2 < 4; j2++) {
                    int kk = half * 8 + 2 * j2;
                    *(int*)&B_l[c * ROWHW + 48 + half * 8 + 2 * j2] =
                        f2bf(qv[kk]) | (f2bf(qv[kk + 1]) << 16);
                }
            } else {
                int dy = 2 * p + dyl;
                float s0=0.f,s1=0.f,s2=0.f,s3=0.f,s4=0.f,s5=0.f,s6=0.f,s7=0.f;
                #pragma unroll
                for (int k = 0; k < 16; k++) {
                    short8 e8 = *(const short8*)&embp[(k * RR + dy) * 16 + half * 8];
                    float qk = qv[k];
                    s0 = fmaf(qk, __builtin_bit_cast(float, ((unsigned)(unsigned short)e8[0]) << 16), s0);
                    s1 = fmaf(qk, __builtin_bit_cast(float, ((unsigned)(unsigned short)e8[1]) << 16), s1);
                    s2 = fmaf(qk, __builtin_bit_cast(float, ((unsigned)(unsigned short)e8[2]) << 16), s2);
                    s3 = fmaf(qk, __builtin_bit_cast(float, ((unsigned)(unsigned short)e8[3]) << 16), s3);
                    s4 = fmaf(qk, __builtin_bit_cast(float, ((unsigned)(unsigned short)e8[4]) << 16), s4);
                    s5 = fmaf(qk, __builtin_bit_cast(float, ((unsigned)(unsigned short)e8[5]) << 16), s5);
                    s6 = fmaf(qk, __builtin_bit_cast(float, ((unsigned)(unsigned short)e8[6]) << 16), s6);
                    s7 = fmaf(qk, __builtin_bit_cast(float, ((unsigned)(unsigned short)e8[7]) << 16), s7);
                }
                float sarr[8] = {s0,s1,s2,s3,s4,s5,s6,s7};
                int base = c * ROWHW + dyl * 48 + x + half * 8 + 1;
                #pragma unroll
                for (int j = 0; j < 8; j++) {
                    int dx = half * 8 + j;
                    if (dx < RR)
                        ((unsigned short*)B_l)[base + j] = (unsigned short)f2bf(sarr[j]);
                }
            }
        }
    };

    f32x4 acc[4][4];
    #pragma unroll
    for (int mr = 0; mr < 4; mr++)
        #pragma unroll
        for (int nr = 0; nr < 4; nr++) acc[mr][nr] = f32x4{0.f, 0.f, 0.f, 0.f};

    build(0);
    __syncthreads();

    for (int p = 0; p < 8; p++) {
        const int nch = (p < 7) ? 3 : 2;
        for (int ch = 0; ch < nch; ch++) {
            short8 a_f[4], b_f[4];
            #pragma unroll
            for (int mr = 0; mr < 4; mr++)
                a_f[mr] = *(const short8*)&A_l[(wm + mr * 16 + r15) * ROWHW + ch * 32 + sl * 8];
            #pragma unroll
            for (int nr = 0; nr < 4; nr++)
                b_f[nr] = *(const short8*)&B_l[(wn + nr * 16 + r15) * ROWHW + ch * 32 + sl * 8];
            #pragma unroll
            for (int mr = 0; mr < 4; mr++)
                #pragma unroll
                for (int nr = 0; nr < 4; nr++)
                    acc[mr][nr] = __builtin_amdgcn_mfma_f32_16x16x32_bf16(
                        a_f[mr], b_f[nr], acc[mr][nr], 0, 0, 0);
        }
        __syncthreads();
        if (p < 7) { build(p + 1); __syncthreads(); }
    }

    // ---- epilogue: D frag = (col=lane&15, row=(lane>>4)*4+i)
    float* ob = out + (size_t)b * 512 * NPOS + (size_t)y * 32;
    #pragma unroll
    for (int mr = 0; mr < 4; mr++) {
        #pragma unroll
        for (int nr = 0; nr < 4; nr++) {
            int vrow = wm + mr * 16 + sl * 4;
            int cc   = wn + nr * 16 + r15;
            int hh   = cc >> 5, xx = cc & 31;
            #pragma unroll
            for (int i = 0; i < 4; i++)
                ob[(size_t)(hh * 128 + vrow + i) * NPOS + xx] = acc[mr][nr][i];
        }
    }
}

// ---------------------------------------------------------------------------
extern "C" void kernel_launch(void* const* d_in, const int* in_sizes, int n_in,
                              void* d_out, int out_size, void* d_ws, size_t ws_size,
                              hipStream_t stream)
{
    const float* x   = (const float*)d_in[0];
    const float* wq  = (const float*)d_in[1];
    const float* wk  = (const float*)d_in[2];
    const float* wv  = (const float*)d_in[3];
    const float* emb = (const float*)d_in[4];
    const float* qg  = (const float*)d_in[5];
    const float* qb  = (const float*)d_in[6];
    const float* vg  = (const float*)d_in[7];
    const float* vb  = (const float*)d_in[8];
    float* out = (float*)d_out;
    float* ws  = (float*)d_ws;

    hipLaunchKernelGGL(proj_kernel, dim3(BATCH * 4 * 13), dim3(256), 0, stream,
                       x, wq, wk, wv, qg, qb, vg, vb, ws);
    hipLaunchKernelGGL(cl_kernel, dim3(BATCH * DV), dim3(64), 0, stream, ws);
    hipLaunchKernelGGL(out_kernel, dim3(BATCH * 32), dim3(256), 0, stream, emb, ws, out);
}

// Round 4
// 144.817 us; speedup vs baseline: 3.7491x; 2.4230x over previous
//
#include <hip/hip_runtime.h>
#include <hip/hip_bf16.h>
#include <math.h>

// LambdaLayer: B=32, DIM=512, H=W=32 (N=1024), DIM_K=16, HEADS=4, DIM_V=128, R=15
#define BATCH 32
#define DIMC  512
#define HGT   32
#define WID   32
#define NPOS  1024
#define DK    16
#define NHEADS 4
#define DV    128
#define RR    15
#define NQ    64

typedef __attribute__((ext_vector_type(8))) short short8;
typedef __attribute__((ext_vector_type(4))) float f32x4;
typedef unsigned short ushort_t;
typedef unsigned int uint_t;

// ws layout in ushort units:
static constexpr size_t U_WB   = 0;                       // [256][512] bf16
static constexpr size_t U_BIAS = 131072;                  // [256] f32 (512 ushorts)
static constexpr size_t U_Q    = 131584;                  // [B][64][1024] bf16
static constexpr size_t U_KSM  = U_Q   + (size_t)BATCH * NQ * NPOS;   // [B][16][1024] bf16
static constexpr size_t U_V    = U_KSM + (size_t)BATCH * DK * NPOS;   // [B][128][1024] bf16
static constexpr size_t U_CL   = U_V   + (size_t)BATCH * DV * NPOS;   // [B][128][16] bf16 ([v][k]!)

static __device__ __forceinline__ uint_t f2bf(float f) {
    return (uint_t)__builtin_bit_cast(unsigned short, __float2bfloat16(f));
}
static __device__ __forceinline__ float bf2f(ushort_t u) {
    return __builtin_bit_cast(float, ((uint_t)u) << 16);
}

// ---------------------------------------------------------------------------
// K0: weight prep — fold BN scale into bf16 weight rows, build bias vector.
// ---------------------------------------------------------------------------
__global__ __launch_bounds__(256) void wprep_kernel(
    const float* __restrict__ wq, const float* __restrict__ wk,
    const float* __restrict__ wv,
    const float* __restrict__ qg, const float* __restrict__ qb,
    const float* __restrict__ vg, const float* __restrict__ vb,
    ushort_t* __restrict__ ws_u)
{
    const int r = blockIdx.x;
    const int t = threadIdx.x;
    const float bninv = 1.0f / sqrtf(1.0f + 1e-5f);

    const float* src = nullptr; float scale = 0.f, bias = 0.f;
    if (r < 64)       { src = wq + (size_t)r * 512;        scale = qg[r] * bninv;      bias = qb[r]; }
    else if (r < 80)  { src = wk + (size_t)(r - 64) * 512; scale = 1.f;                bias = 0.f; }
    else if (r < 208) { src = wv + (size_t)(r - 80) * 512; scale = vg[r - 80] * bninv; bias = vb[r - 80]; }

    #pragma unroll
    for (int i = 0; i < 2; i++) {
        int cc = t + i * 256;
        float v = src ? src[cc] * scale : 0.f;
        ws_u[U_WB + (size_t)r * 512 + cc] = (ushort_t)f2bf(v);
    }
    if (t == 0) ((float*)(ws_u + U_BIAS))[r] = bias;
}

// ---------------------------------------------------------------------------
// K1: fused projection GEMM (bf16 MFMA): Out[256][128] = W[256][512] @ X[512][128]
// ---------------------------------------------------------------------------
#define BSTR 72

__global__ __launch_bounds__(512) void proj_mfma_kernel(
    const float* __restrict__ x, ushort_t* __restrict__ ws_u)
{
    __shared__ ushort_t B_l[128 * BSTR];
    __shared__ float bias_l[256];

    const int t  = threadIdx.x;
    const int b  = blockIdx.x >> 3;
    const int n0 = (blockIdx.x & 7) * 128;
    const int lane = t & 63;
    const int w  = t >> 6;
    const int wm = w & 3;
    const int wn = w >> 2;
    const int r15 = lane & 15;
    const int sl  = lane >> 4;

    if (t < 256) bias_l[t] = ((const float*)(ws_u + U_BIAS))[t];

    const float* xb = x + (size_t)b * DIMC * NPOS + n0;
    const ushort_t* wb = ws_u + U_WB;

    float xr[16];
    auto issue = [&](int c) {
        #pragma unroll
        for (int i = 0; i < 8; i++) {
            int idx = i * 512 + t;
            int n  = (idx & 15) | (((idx >> 6) & 7) << 4);
            int dp = ((idx >> 4) & 3) | (((idx >> 9) & 7) << 2);
            int d  = c * 64 + 2 * dp;
            xr[2 * i]     = xb[(size_t)d * NPOS + n];
            xr[2 * i + 1] = xb[(size_t)(d + 1) * NPOS + n];
        }
    };
    auto commit = [&]() {
        #pragma unroll
        for (int i = 0; i < 8; i++) {
            int idx = i * 512 + t;
            int n  = (idx & 15) | (((idx >> 6) & 7) << 4);
            int dp = ((idx >> 4) & 3) | (((idx >> 9) & 7) << 2);
            *(uint_t*)&B_l[n * BSTR + 2 * dp] = f2bf(xr[2 * i]) | (f2bf(xr[2 * i + 1]) << 16);
        }
    };

    f32x4 acc[4][4];
    #pragma unroll
    for (int mt = 0; mt < 4; mt++)
        #pragma unroll
        for (int nt = 0; nt < 4; nt++) acc[mt][nt] = f32x4{0.f, 0.f, 0.f, 0.f};

    issue(0);
    for (int c = 0; c < 8; c++) {
        __syncthreads();
        commit();
        if (c < 7) issue(c + 1);
        __syncthreads();
        #pragma unroll
        for (int kk = 0; kk < 2; kk++) {
            short8 a_f[4], b_f[4];
            #pragma unroll
            for (int mt = 0; mt < 4; mt++) {
                int row = wm * 64 + mt * 16 + r15;
                a_f[mt] = *(const short8*)&wb[(size_t)row * 512 + c * 64 + kk * 32 + sl * 8];
            }
            #pragma unroll
            for (int nt = 0; nt < 4; nt++) {
                int col = wn * 64 + nt * 16 + r15;
                b_f[nt] = *(const short8*)&B_l[col * BSTR + kk * 32 + sl * 8];
            }
            #pragma unroll
            for (int mt = 0; mt < 4; mt++)
                #pragma unroll
                for (int nt = 0; nt < 4; nt++)
                    acc[mt][nt] = __builtin_amdgcn_mfma_f32_16x16x32_bf16(
                        a_f[mt], b_f[nt], acc[mt][nt], 0, 0, 0);
        }
    }

    ushort_t* qp = ws_u + U_Q   + (size_t)b * NQ * NPOS;
    ushort_t* kp = ws_u + U_KSM + (size_t)b * DK * NPOS;
    ushort_t* vp = ws_u + U_V   + (size_t)b * DV * NPOS;

    #pragma unroll
    for (int mt = 0; mt < 4; mt++) {
        int row0 = wm * 64 + mt * 16;
        if (row0 >= 208) continue;
        if (row0 == 64) {               // k tile -> column softmax over 16 rows
            #pragma unroll
            for (int nt = 0; nt < 4; nt++) {
                int col = n0 + wn * 64 + nt * 16 + r15;
                f32x4 v = acc[mt][nt];
                float m = fmaxf(fmaxf(v[0], v[1]), fmaxf(v[2], v[3]));
                m = fmaxf(m, __shfl_xor(m, 16));
                m = fmaxf(m, __shfl_xor(m, 32));
                float e[4];
                float s = 0.f;
                #pragma unroll
                for (int i = 0; i < 4; i++) { e[i] = __expf(v[i] - m); s += e[i]; }
                s += __shfl_xor(s, 16);
                s += __shfl_xor(s, 32);
                float r = 1.0f / s;
                #pragma unroll
                for (int i = 0; i < 4; i++) {
                    int krow = sl * 4 + i;
                    kp[(size_t)krow * NPOS + col] = (ushort_t)f2bf(e[i] * r);
                }
            }
        } else {
            bool isq = row0 < 64;
            #pragma unroll
            for (int nt = 0; nt < 4; nt++) {
                int col = n0 + wn * 64 + nt * 16 + r15;
                #pragma unroll
                for (int i = 0; i < 4; i++) {
                    int row = row0 + sl * 4 + i;
                    float val = acc[mt][nt][i] + bias_l[row];
                    if (isq) qp[(size_t)row * NPOS + col] = (ushort_t)f2bf(val);
                    else     vp[(size_t)(row - 80) * NPOS + col] = (ushort_t)f2bf(val);
                }
            }
        }
    }
}

// ---------------------------------------------------------------------------
// K2: content_lambda[b][v][k]
// ---------------------------------------------------------------------------
__global__ __launch_bounds__(64) void cl_kernel(ushort_t* __restrict__ ws_u)
{
    const int bid = (int)((blockIdx.x & 7) * 512 + (blockIdx.x >> 3));
    const int lane = threadIdx.x;
    const int v = bid & 127;
    const int b = bid >> 7;

    const ushort_t* vrow = ws_u + U_V   + ((size_t)b * DV + v) * NPOS;
    const ushort_t* kb   = ws_u + U_KSM + (size_t)b * DK * NPOS;

    float acc[16];
    #pragma unroll
    for (int k = 0; k < 16; k++) acc[k] = 0.f;

    for (int i = 0; i < 16; i++) {
        int n = i * 64 + lane;
        float vv = bf2f(vrow[n]);
        #pragma unroll
        for (int k = 0; k < 16; k++)
            acc[k] = fmaf(bf2f(kb[(size_t)k * NPOS + n]), vv, acc[k]);
    }

    ushort_t* clp = ws_u + U_CL + ((size_t)b * DV + v) * 16;
    #pragma unroll
    for (int k = 0; k < 16; k++) {
        float s = acc[k];
        #pragma unroll
        for (int off = 32; off > 0; off >>= 1) s += __shfl_down(s, off);
        if (lane == 0) clp[k] = (ushort_t)f2bf(s);
    }
}

// ---------------------------------------------------------------------------
// K3: banded-GEMM out kernel
// ---------------------------------------------------------------------------
#define ROWHW 104

__global__ __launch_bounds__(256) void out_kernel(
    const float* __restrict__ emb, const ushort_t* __restrict__ ws_u,
    float* __restrict__ out)
{
    __shared__ ushort_t A_l[DV * ROWHW];
    __shared__ ushort_t B_l[128 * ROWHW];
    __shared__ ushort_t embp_l[DK * 2 * 16];

    const int t = threadIdx.x;
    const int bid = (int)((blockIdx.x & 7) * 128 + (blockIdx.x >> 3));
    const int b = bid >> 5;
    const int y = bid & 31;
    const int lane = t & 63;
    const int w = t >> 6;
    const int wm = (w & 1) * 64;
    const int wn = (w >> 1) * 64;
    const int r15 = lane & 15;
    const int sl  = lane >> 4;

    const int c    = t >> 1;
    const int h    = c >> 5;
    const int x    = c & 31;
    const int half = t & 1;

    const ushort_t* Vb  = ws_u + U_V  + (size_t)b * DV * NPOS;
    const ushort_t* CLb = ws_u + U_CL + (size_t)b * DV * 16;

    ushort_t qbits[16]; float qv[16];
    {
        const ushort_t* qp = ws_u + U_Q + ((size_t)b * NQ + h * 16) * NPOS + y * 32 + x;
        #pragma unroll
        for (int k = 0; k < 16; k++) {
            ushort_t u = qp[(size_t)k * NPOS];
            qbits[k] = u;
            qv[k] = bf2f(u);
        }
    }

    int4 ar[4]; float er[2];
    auto a_issue = [&](int p) {
        #pragma unroll
        for (int rep = 0; rep < 4; rep++) {
            int idx = rep * 256 + t;
            int v   = idx >> 3;
            int dyl = (idx >> 2) & 1;
            int j   = idx & 3;
            int4 val; val.x = 0; val.y = 0; val.z = 0; val.w = 0;
            if (p == 7 && dyl == 1) {
                if (j < 2) val = *(const int4*)&CLb[v * 16 + 8 * j];   // 8 bf16: k=8j..8j+7
            } else {
                int yy = y + 2 * p + dyl - 7;
                if (yy >= 0 && yy < HGT)
                    val = *(const int4*)&Vb[(size_t)v * NPOS + yy * 32 + 8 * j]; // 8 px
            }
            ar[rep] = val;
        }
        #pragma unroll
        for (int e = 0; e < 2; e++) {
            int el = 2 * t + e;
            int kd = el >> 5, dyl = (el >> 4) & 1, dx = el & 15;
            int dy = 2 * p + dyl;
            er[e] = (dx < RR && dy < RR) ? emb[kd * (RR * RR) + dy * RR + dx] : 0.f;
        }
    };
    auto a_commit = [&](int p) {
        #pragma unroll
        for (int rep = 0; rep < 4; rep++) {
            int idx = rep * 256 + t;
            int v   = idx >> 3;
            int dyl = (idx >> 2) & 1;
            int j   = idx & 3;
            if (p == 7 && dyl == 1) {
                if (j < 2) *(int4*)&A_l[v * ROWHW + 48 + 8 * j] = ar[rep];
            } else {
                *(int4*)&A_l[v * ROWHW + dyl * 48 + 8 + 8 * j] = ar[rep];
            }
        }
        #pragma unroll
        for (int e = 0; e < 2; e++)
            embp_l[2 * t + e] = (ushort_t)f2bf(er[e]);
    };
    auto qe_build = [&](int p) {
        #pragma unroll
        for (int dyl = 0; dyl < 2; dyl++) {
            if (p == 7 && dyl == 1) {
                #pragma unroll
                for (int j2 = 0; j2 < 4; j2++) {
                    int kk = half * 8 + 2 * j2;
                    *(uint_t*)&B_l[c * ROWHW + 48 + kk] =
                        (uint_t)qbits[kk] | ((uint_t)qbits[kk + 1] << 16);
                }
            } else {
                float s[8];
                #pragma unroll
                for (int j = 0; j < 8; j++) s[j] = 0.f;
                #pragma unroll
                for (int k = 0; k < 16; k++) {
                    short8 e8 = *(const short8*)&embp_l[(k * 2 + dyl) * 16 + half * 8];
                    float qk = qv[k];
                    #pragma unroll
                    for (int j = 0; j < 8; j++)
                        s[j] = fmaf(qk, bf2f((ushort_t)e8[j]), s[j]);
                }
                int base = c * ROWHW + dyl * 48 + x + half * 8 + 1;
                #pragma unroll
                for (int j = 0; j < 8; j++)
                    if (half * 8 + j < RR) B_l[base + j] = (ushort_t)f2bf(s[j]);
            }
        }
    };

    a_issue(0);
    {
        int* a4 = (int*)A_l; int* b4 = (int*)B_l;
        for (int i = t; i < 6656; i += 256) { a4[i] = 0; b4[i] = 0; }
    }
    __syncthreads();
    a_commit(0);
    __syncthreads();
    qe_build(0);

    f32x4 acc[4][4];
    #pragma unroll
    for (int mr = 0; mr < 4; mr++)
        #pragma unroll
        for (int nr = 0; nr < 4; nr++) acc[mr][nr] = f32x4{0.f, 0.f, 0.f, 0.f};
    __syncthreads();

    for (int p = 0; p < 8; p++) {
        if (p < 7) a_issue(p + 1);
        const int nch = (p < 7) ? 3 : 2;
        for (int ch = 0; ch < nch; ch++) {
            short8 a_f[4], b_f[4];
            #pragma unroll
            for (int mr = 0; mr < 4; mr++)
                a_f[mr] = *(const short8*)&A_l[(wm + mr * 16 + r15) * ROWHW + ch * 32 + sl * 8];
            #pragma unroll
            for (int nr = 0; nr < 4; nr++)
                b_f[nr] = *(const short8*)&B_l[(wn + nr * 16 + r15) * ROWHW + ch * 32 + sl * 8];
            #pragma unroll
            for (int mr = 0; mr < 4; mr++)
                #pragma unroll
                for (int nr = 0; nr < 4; nr++)
                    acc[mr][nr] = __builtin_amdgcn_mfma_f32_16x16x32_bf16(
                        a_f[mr], b_f[nr], acc[mr][nr], 0, 0, 0);
        }
        if (p == 7) break;
        __syncthreads();
        a_commit(p + 1);
        __syncthreads();
        qe_build(p + 1);
        __syncthreads();
    }

    float* ob = out + (size_t)b * 512 * NPOS + (size_t)y * 32;
    #pragma unroll
    for (int mr = 0; mr < 4; mr++) {
        #pragma unroll
        for (int nr = 0; nr < 4; nr++) {
            int vrow = wm + mr * 16 + sl * 4;
            int cc   = wn + nr * 16 + r15;
            int hh   = cc >> 5, xx = cc & 31;
            #pragma unroll
            for (int i = 0; i < 4; i++)
                ob[(size_t)(hh * 128 + vrow + i) * NPOS + xx] = acc[mr][nr][i];
        }
    }
}

// ---------------------------------------------------------------------------
extern "C" void kernel_launch(void* const* d_in, const int* in_sizes, int n_in,
                              void* d_out, int out_size, void* d_ws, size_t ws_size,
                              hipStream_t stream)
{
    const float* x   = (const float*)d_in[0];
    const float* wq  = (const float*)d_in[1];
    const float* wk  = (const float*)d_in[2];
    const float* wv  = (const float*)d_in[3];
    const float* emb = (const float*)d_in[4];
    const float* qg  = (const float*)d_in[5];
    const float* qb  = (const float*)d_in[6];
    const float* vg  = (const float*)d_in[7];
    const float* vb  = (const float*)d_in[8];
    float* out = (float*)d_out;
    ushort_t* ws_u = (ushort_t*)d_ws;

    hipLaunchKernelGGL(wprep_kernel, dim3(256), dim3(256), 0, stream,
                       wq, wk, wv, qg, qb, vg, vb, ws_u);
    hipLaunchKernelGGL(proj_mfma_kernel, dim3(BATCH * 8), dim3(512), 0, stream,
                       x, ws_u);
    hipLaunchKernelGGL(cl_kernel, dim3(BATCH * DV), dim3(64), 0, stream, ws_u);
    hipLaunchKernelGGL(out_kernel, dim3(BATCH * 32), dim3(256), 0, stream,
                       emb, ws_u, out);
}

// Round 5
// 94.714 us; speedup vs baseline: 5.7323x; 1.5290x over previous
//
#include <hip/hip_runtime.h>
#include <hip/hip_bf16.h>
#include <math.h>

// LambdaLayer: B=32, DIM=512, H=W=32 (N=1024), DIM_K=16, HEADS=4, DIM_V=128, R=15
#define BATCH 32
#define DIMC  512
#define HGT   32
#define WID   32
#define NPOS  1024
#define DK    16
#define NHEADS 4
#define DV    128
#define RR    15
#define NQ    64

typedef __attribute__((ext_vector_type(8))) short short8;
typedef __attribute__((ext_vector_type(4))) float f32x4;
typedef unsigned short ushort_t;
typedef unsigned int uint_t;

// ws layout in ushort units:
static constexpr size_t U_WB   = 0;                       // [256][512] bf16
static constexpr size_t U_BIAS = 131072;                  // [256] f32 (512 ushorts)
static constexpr size_t U_Q    = 131584;                  // [B][64][1024] bf16
static constexpr size_t U_KSM  = U_Q   + (size_t)BATCH * NQ * NPOS;   // [B][16][1024] bf16
static constexpr size_t U_V    = U_KSM + (size_t)BATCH * DK * NPOS;   // [B][128][1024] bf16
static constexpr size_t U_CL   = U_V   + (size_t)BATCH * DV * NPOS;   // [B][128][16] bf16 ([v][k])

static __device__ __forceinline__ uint_t f2bf(float f) {
    return (uint_t)__builtin_bit_cast(unsigned short, __float2bfloat16(f));
}
static __device__ __forceinline__ float bf2f(ushort_t u) {
    return __builtin_bit_cast(float, ((uint_t)u) << 16);
}

// ---------------------------------------------------------------------------
// K0: weight prep — fold BN scale into bf16 weight rows, build bias vector.
// ---------------------------------------------------------------------------
__global__ __launch_bounds__(256) void wprep_kernel(
    const float* __restrict__ wq, const float* __restrict__ wk,
    const float* __restrict__ wv,
    const float* __restrict__ qg, const float* __restrict__ qb,
    const float* __restrict__ vg, const float* __restrict__ vb,
    ushort_t* __restrict__ ws_u)
{
    const int r = blockIdx.x;
    const int t = threadIdx.x;
    const float bninv = 1.0f / sqrtf(1.0f + 1e-5f);

    const float* src = nullptr; float scale = 0.f, bias = 0.f;
    if (r < 64)       { src = wq + (size_t)r * 512;        scale = qg[r] * bninv;      bias = qb[r]; }
    else if (r < 80)  { src = wk + (size_t)(r - 64) * 512; scale = 1.f;                bias = 0.f; }
    else if (r < 208) { src = wv + (size_t)(r - 80) * 512; scale = vg[r - 80] * bninv; bias = vb[r - 80]; }

    #pragma unroll
    for (int i = 0; i < 2; i++) {
        int cc = t + i * 256;
        float v = src ? src[cc] * scale : 0.f;
        ws_u[U_WB + (size_t)r * 512 + cc] = (ushort_t)f2bf(v);
    }
    if (t == 0) ((float*)(ws_u + U_BIAS))[r] = bias;
}

// ---------------------------------------------------------------------------
// K1: fused projection GEMM (bf16 MFMA): Out[256][128] = W[256][512] @ X[512][128]
// ---------------------------------------------------------------------------
#define BSTR 72

__global__ __launch_bounds__(512) void proj_mfma_kernel(
    const float* __restrict__ x, ushort_t* __restrict__ ws_u)
{
    __shared__ ushort_t B_l[128 * BSTR];
    __shared__ float bias_l[256];

    const int t  = threadIdx.x;
    const int b  = blockIdx.x >> 3;
    const int n0 = (blockIdx.x & 7) * 128;
    const int lane = t & 63;
    const int w  = t >> 6;
    const int wm = w & 3;
    const int wn = w >> 2;
    const int r15 = lane & 15;
    const int sl  = lane >> 4;

    if (t < 256) bias_l[t] = ((const float*)(ws_u + U_BIAS))[t];

    const float* xb = x + (size_t)b * DIMC * NPOS + n0;
    const ushort_t* wb = ws_u + U_WB;

    float xr[16];
    auto issue = [&](int c) {
        #pragma unroll
        for (int i = 0; i < 8; i++) {
            int idx = i * 512 + t;
            int n  = (idx & 15) | (((idx >> 6) & 7) << 4);
            int dp = ((idx >> 4) & 3) | (((idx >> 9) & 7) << 2);
            int d  = c * 64 + 2 * dp;
            xr[2 * i]     = xb[(size_t)d * NPOS + n];
            xr[2 * i + 1] = xb[(size_t)(d + 1) * NPOS + n];
        }
    };
    auto commit = [&]() {
        #pragma unroll
        for (int i = 0; i < 8; i++) {
            int idx = i * 512 + t;
            int n  = (idx & 15) | (((idx >> 6) & 7) << 4);
            int dp = ((idx >> 4) & 3) | (((idx >> 9) & 7) << 2);
            *(uint_t*)&B_l[n * BSTR + 2 * dp] = f2bf(xr[2 * i]) | (f2bf(xr[2 * i + 1]) << 16);
        }
    };

    f32x4 acc[4][4];
    #pragma unroll
    for (int mt = 0; mt < 4; mt++)
        #pragma unroll
        for (int nt = 0; nt < 4; nt++) acc[mt][nt] = f32x4{0.f, 0.f, 0.f, 0.f};

    issue(0);
    for (int c = 0; c < 8; c++) {
        __syncthreads();
        commit();
        if (c < 7) issue(c + 1);
        __syncthreads();
        #pragma unroll
        for (int kk = 0; kk < 2; kk++) {
            short8 a_f[4], b_f[4];
            #pragma unroll
            for (int mt = 0; mt < 4; mt++) {
                int row = wm * 64 + mt * 16 + r15;
                a_f[mt] = *(const short8*)&wb[(size_t)row * 512 + c * 64 + kk * 32 + sl * 8];
            }
            #pragma unroll
            for (int nt = 0; nt < 4; nt++) {
                int col = wn * 64 + nt * 16 + r15;
                b_f[nt] = *(const short8*)&B_l[col * BSTR + kk * 32 + sl * 8];
            }
            #pragma unroll
            for (int mt = 0; mt < 4; mt++)
                #pragma unroll
                for (int nt = 0; nt < 4; nt++)
                    acc[mt][nt] = __builtin_amdgcn_mfma_f32_16x16x32_bf16(
                        a_f[mt], b_f[nt], acc[mt][nt], 0, 0, 0);
        }
    }

    ushort_t* qp = ws_u + U_Q   + (size_t)b * NQ * NPOS;
    ushort_t* kp = ws_u + U_KSM + (size_t)b * DK * NPOS;
    ushort_t* vp = ws_u + U_V   + (size_t)b * DV * NPOS;

    #pragma unroll
    for (int mt = 0; mt < 4; mt++) {
        int row0 = wm * 64 + mt * 16;
        if (row0 >= 208) continue;
        if (row0 == 64) {               // k tile -> column softmax over 16 rows
            #pragma unroll
            for (int nt = 0; nt < 4; nt++) {
                int col = n0 + wn * 64 + nt * 16 + r15;
                f32x4 v = acc[mt][nt];
                float m = fmaxf(fmaxf(v[0], v[1]), fmaxf(v[2], v[3]));
                m = fmaxf(m, __shfl_xor(m, 16));
                m = fmaxf(m, __shfl_xor(m, 32));
                float e[4];
                float s = 0.f;
                #pragma unroll
                for (int i = 0; i < 4; i++) { e[i] = __expf(v[i] - m); s += e[i]; }
                s += __shfl_xor(s, 16);
                s += __shfl_xor(s, 32);
                float r = 1.0f / s;
                #pragma unroll
                for (int i = 0; i < 4; i++) {
                    int krow = sl * 4 + i;
                    kp[(size_t)krow * NPOS + col] = (ushort_t)f2bf(e[i] * r);
                }
            }
        } else {
            bool isq = row0 < 64;
            #pragma unroll
            for (int nt = 0; nt < 4; nt++) {
                int col = n0 + wn * 64 + nt * 16 + r15;
                #pragma unroll
                for (int i = 0; i < 4; i++) {
                    int row = row0 + sl * 4 + i;
                    float val = acc[mt][nt][i] + bias_l[row];
                    if (isq) qp[(size_t)row * NPOS + col] = (ushort_t)f2bf(val);
                    else     vp[(size_t)(row - 80) * NPOS + col] = (ushort_t)f2bf(val);
                }
            }
        }
    }
}

// ---------------------------------------------------------------------------
// K2: content_lambda[b][v][k]
// ---------------------------------------------------------------------------
__global__ __launch_bounds__(64) void cl_kernel(ushort_t* __restrict__ ws_u)
{
    const int bid = (int)((blockIdx.x & 7) * 512 + (blockIdx.x >> 3));
    const int lane = threadIdx.x;
    const int v = bid & 127;
    const int b = bid >> 7;

    const ushort_t* vrow = ws_u + U_V   + ((size_t)b * DV + v) * NPOS;
    const ushort_t* kb   = ws_u + U_KSM + (size_t)b * DK * NPOS;

    float acc[16];
    #pragma unroll
    for (int k = 0; k < 16; k++) acc[k] = 0.f;

    for (int i = 0; i < 16; i++) {
        int n = i * 64 + lane;
        float vv = bf2f(vrow[n]);
        #pragma unroll
        for (int k = 0; k < 16; k++)
            acc[k] = fmaf(bf2f(kb[(size_t)k * NPOS + n]), vv, acc[k]);
    }

    ushort_t* clp = ws_u + U_CL + ((size_t)b * DV + v) * 16;
    #pragma unroll
    for (int k = 0; k < 16; k++) {
        float s = acc[k];
        #pragma unroll
        for (int off = 32; off > 0; off >>= 1) s += __shfl_down(s, off);
        if (lane == 0) clp[k] = (ushort_t)f2bf(s);
    }
}

// ---------------------------------------------------------------------------
// K3: banded-GEMM out kernel, 512 threads, qe via MFMA.
//   Out[v=128][c=(h,x)=128]; K = 8 pairs (96,96,...,96,64 halfword cols).
//   A[v][*]: v-slab rows (image rows y+2p+dyl-7 at chunk cols 8..39) + CL.
//   B[c][*]: band qe: B[c][dyl*48 + x+dx+1] = qe[c][dy=2p+dyl][dx], built by
//   MFMA: qe[c][j=(dy,dx)] = sum_k Qt[c][k]*ebt[j][k], scattered per pair.
// ---------------------------------------------------------------------------
#define ROWHW 104

__global__ __launch_bounds__(512, 4) void out_kernel(
    const float* __restrict__ emb, const ushort_t* __restrict__ ws_u,
    float* __restrict__ out)
{
    __shared__ ushort_t A_l[DV * ROWHW];        // 26624 B
    __shared__ ushort_t B_l[128 * ROWHW];       // 26624 B
    __shared__ ushort_t Qt_l[128 * 16];         // 4096 B  [c][k]
    __shared__ ushort_t ebt_l[256 * 16];        // 8192 B  [dy*16+dx][k] (pad)

    const int t = threadIdx.x;
    const int bid = (int)((blockIdx.x & 7) * 128 + (blockIdx.x >> 3));
    const int b = bid >> 5;
    const int y = bid & 31;
    const int lane = t & 63;
    const int w = t >> 6;            // 0..7
    const int wm = (w & 1) * 64;     // M base
    const int wn = (w >> 1) * 32;    // N base
    const int r15 = lane & 15;
    const int sl  = lane >> 4;

    const ushort_t* Vb  = ws_u + U_V  + (size_t)b * DV * NPOS;
    const ushort_t* CLb = ws_u + U_CL + (size_t)b * DV * 16;

    const short8 z8 = {0, 0, 0, 0, 0, 0, 0, 0};

    int4 ar[2];
    auto a_issue = [&](int p) {
        #pragma unroll
        for (int rep = 0; rep < 2; rep++) {
            int idx = rep * 512 + t;
            int v   = idx >> 3;
            int dyl = (idx >> 2) & 1;
            int j   = idx & 3;
            int4 val; val.x = 0; val.y = 0; val.z = 0; val.w = 0;
            if (p == 7 && dyl == 1) {
                if (j < 2) val = *(const int4*)&CLb[v * 16 + 8 * j];
            } else {
                int yy = y + 2 * p + dyl - 7;
                if (yy >= 0 && yy < HGT)
                    val = *(const int4*)&Vb[(size_t)v * NPOS + yy * 32 + 8 * j];
            }
            ar[rep] = val;
        }
    };
    auto a_commit = [&](int p) {
        #pragma unroll
        for (int rep = 0; rep < 2; rep++) {
            int idx = rep * 512 + t;
            int v   = idx >> 3;
            int dyl = (idx >> 2) & 1;
            int j   = idx & 3;
            if (p == 7 && dyl == 1) {
                if (j < 2) *(int4*)&A_l[v * ROWHW + 48 + 8 * j] = ar[rep];
            } else {
                *(int4*)&A_l[v * ROWHW + dyl * 48 + 8 + 8 * j] = ar[rep];
            }
        }
    };

    f32x4 qacc[2];
    auto qe_mfma = [&](int pn) {
        short8 qa = (sl < 2) ? *(const short8*)&Qt_l[(w * 16 + r15) * 16 + sl * 8] : z8;
        #pragma unroll
        for (int jt = 0; jt < 2; jt++) {
            short8 eb = (sl < 2)
                ? *(const short8*)&ebt_l[(pn * 32 + jt * 16 + r15) * 16 + sl * 8] : z8;
            qacc[jt] = __builtin_amdgcn_mfma_f32_16x16x32_bf16(
                qa, eb, f32x4{0.f, 0.f, 0.f, 0.f}, 0, 0, 0);
        }
    };
    auto qe_scatter = [&](int pn) {
        #pragma unroll
        for (int jt = 0; jt < 2; jt++) {
            if (pn == 7 && jt == 1) continue;
            if (r15 < 15) {
                #pragma unroll
                for (int i = 0; i < 4; i++) {
                    int c = w * 16 + sl * 4 + i;
                    B_l[c * ROWHW + jt * 48 + (c & 31) + r15 + 1] =
                        (ushort_t)f2bf(qacc[jt][i]);
                }
            }
        }
        if (pn == 7) {   // content chunk: B[c][48+k] = Qt[c][k]
            #pragma unroll
            for (int rep = 0; rep < 2; rep++) {
                int d = rep * 512 + t;        // 0..1023 dwords
                int c = d >> 3, kk = (d & 7) * 2;
                *(uint_t*)&B_l[c * ROWHW + 48 + kk] = *(const uint_t*)&Qt_l[c * 16 + kk];
            }
        }
    };

    // ---- prologue: zero A/B, stage Qt + ebt, issue pair-0
    {
        int* a4 = (int*)A_l; int* b4 = (int*)B_l;
        for (int i = t; i < 6656; i += 512) { a4[i] = 0; b4[i] = 0; }
    }
    {   // Qt[c][k] = Q[b][ (c>>5)*16 + k ][ y*32 + (c&31) ]
        int c = t >> 2;
        const ushort_t* qp = ws_u + U_Q + ((size_t)b * NQ + (c >> 5) * 16) * NPOS
                           + y * 32 + (c & 31);
        #pragma unroll
        for (int i = 0; i < 4; i++) {
            int k = (t & 3) * 4 + i;
            Qt_l[c * 16 + k] = qp[(size_t)k * NPOS];
        }
    }
    {   // ebt[r=(dy*16+dx)][k] = emb[k][dy][dx]; zero for dx==15 or r>=240
        #pragma unroll
        for (int i = 0; i < 8; i++) {
            int idx = t * 8 + i;
            int r = idx >> 4, k = idx & 15;
            float val = 0.f;
            if (r < 240 && (r & 15) < RR)
                val = emb[k * (RR * RR) + (r >> 4) * RR + (r & 15)];
            ebt_l[idx] = (ushort_t)f2bf(val);
        }
    }
    a_issue(0);
    __syncthreads();
    a_commit(0);
    qe_mfma(0);
    qe_scatter(0);
    __syncthreads();

    f32x4 acc[4][2];
    #pragma unroll
    for (int mt = 0; mt < 4; mt++)
        #pragma unroll
        for (int nt = 0; nt < 2; nt++) acc[mt][nt] = f32x4{0.f, 0.f, 0.f, 0.f};

    for (int p = 0; p < 8; p++) {
        if (p < 7) a_issue(p + 1);
        const int nch = (p < 7) ? 3 : 2;
        for (int ch = 0; ch < nch; ch++) {
            short8 a_f[4], b_f[2];
            #pragma unroll
            for (int mt = 0; mt < 4; mt++)
                a_f[mt] = *(const short8*)&A_l[(wm + mt * 16 + r15) * ROWHW + ch * 32 + sl * 8];
            #pragma unroll
            for (int nt = 0; nt < 2; nt++)
                b_f[nt] = *(const short8*)&B_l[(wn + nt * 16 + r15) * ROWHW + ch * 32 + sl * 8];
            #pragma unroll
            for (int mt = 0; mt < 4; mt++)
                #pragma unroll
                for (int nt = 0; nt < 2; nt++)
                    acc[mt][nt] = __builtin_amdgcn_mfma_f32_16x16x32_bf16(
                        a_f[mt], b_f[nt], acc[mt][nt], 0, 0, 0);
        }
        if (p < 7) qe_mfma(p + 1);
        if (p == 7) break;
        __syncthreads();
        a_commit(p + 1);
        qe_scatter(p + 1);
        __syncthreads();
    }

    // ---- epilogue
    float* ob = out + (size_t)b * 512 * NPOS + (size_t)y * 32;
    #pragma unroll
    for (int mt = 0; mt < 4; mt++) {
        #pragma unroll
        for (int nt = 0; nt < 2; nt++) {
            int vrow = wm + mt * 16 + sl * 4;
            int cc   = wn + nt * 16 + r15;
            int hh   = cc >> 5, xx = cc & 31;
            #pragma unroll
            for (int i = 0; i < 4; i++)
                ob[(size_t)(hh * 128 + vrow + i) * NPOS + xx] = acc[mt][nt][i];
        }
    }
}

// ---------------------------------------------------------------------------
extern "C" void kernel_launch(void* const* d_in, const int* in_sizes, int n_in,
                              void* d_out, int out_size, void* d_ws, size_t ws_size,
                              hipStream_t stream)
{
    const float* x   = (const float*)d_in[0];
    const float* wq  = (const float*)d_in[1];
    const float* wk  = (const float*)d_in[2];
    const float* wv  = (const float*)d_in[3];
    const float* emb = (const float*)d_in[4];
    const float* qg  = (const float*)d_in[5];
    const float* qb  = (const float*)d_in[6];
    const float* vg  = (const float*)d_in[7];
    const float* vb  = (const float*)d_in[8];
    float* out = (float*)d_out;
    ushort_t* ws_u = (ushort_t*)d_ws;

    hipLaunchKernelGGL(wprep_kernel, dim3(256), dim3(256), 0, stream,
                       wq, wk, wv, qg, qb, vg, vb, ws_u);
    hipLaunchKernelGGL(proj_mfma_kernel, dim3(BATCH * 8), dim3(512), 0, stream,
                       x, ws_u);
    hipLaunchKernelGGL(cl_kernel, dim3(BATCH * DV), dim3(64), 0, stream, ws_u);
    hipLaunchKernelGGL(out_kernel, dim3(BATCH * 32), dim3(512), 0, stream,
                       emb, ws_u, out);
}